// Round 2
// baseline (325.145 us; speedup 1.0000x reference)
//
#include <hip/hip_runtime.h>
#include <hip/hip_bf16.h>

#define D 512
#define SB 512          // elements per scan block
#define FBM 64          // fused kernel: rows per block

typedef __attribute__((ext_vector_type(8))) short bf16x8;
typedef __attribute__((ext_vector_type(4))) float f32x4;

__device__ __forceinline__ unsigned short bf16_rne(float f) {
    union { float f; unsigned u; } v; v.f = f;
    return (unsigned short)((v.u + 0x7FFFu + ((v.u >> 16) & 1u)) >> 16);
}

__device__ __forceinline__ void facc(float4& a, const float4 v) {
    a.x += v.x; a.y += v.y; a.z += v.z; a.w += v.w;
}

// ---------------- W fp32->bf16 conversion fused with degree histogram ----------------
// blocks [0, 512)          : convert W (512*512 floats, 1 float2/thread)
// blocks [512, 512+HB)     : histogram of dst indices
__global__ __launch_bounds__(256) void prep_kernel(const float* __restrict__ W,
                                                   unsigned short* __restrict__ wb,
                                                   const int* __restrict__ dst, int E,
                                                   int* __restrict__ cnt) {
    const int b = blockIdx.x;
    const int t = threadIdx.x;
    if (b < 512) {
        const int i = b * 256 + t;
        float2 v = ((const float2*)W)[i];
        unsigned r = ((unsigned)bf16_rne(v.x)) | (((unsigned)bf16_rne(v.y)) << 16);
        ((unsigned*)wb)[i] = r;
    } else {
        const int e = (b - 512) * 256 + t;
        if (e < E) atomicAdd(&cnt[dst[e]], 1);
    }
}

// ---------------- CSR build (scan + sort) ----------------

__global__ __launch_bounds__(256) void scan_reduce_kernel(const int* __restrict__ cnt, int M,
                                                          int* __restrict__ bsum) {
    const int t = threadIdx.x;
    const int i0 = blockIdx.x * SB + t * 2;
    int v = 0;
    if (i0 < M)     v += cnt[i0];
    if (i0 + 1 < M) v += cnt[i0 + 1];
    #pragma unroll
    for (int o = 32; o > 0; o >>= 1) v += __shfl_down(v, o, 64);
    __shared__ int ws_[4];
    if ((t & 63) == 0) ws_[t >> 6] = v;
    __syncthreads();
    if (t == 0) bsum[blockIdx.x] = ws_[0] + ws_[1] + ws_[2] + ws_[3];
}

__global__ __launch_bounds__(256) void scan_bsum_kernel(const int* __restrict__ bsum, int NB,
                                                        int* __restrict__ bscan,
                                                        int* __restrict__ offsets, int M) {
    __shared__ int s[256];
    const int t = threadIdx.x;
    int v = (t < NB) ? bsum[t] : 0;
    s[t] = v;
    __syncthreads();
    #pragma unroll
    for (int o = 1; o < 256; o <<= 1) {
        int u = (t >= o) ? s[t - o] : 0;
        __syncthreads();
        s[t] += u;
        __syncthreads();
    }
    if (t < NB) bscan[t] = s[t] - v;
    if (t == 255) offsets[M] = s[255];
}

__global__ __launch_bounds__(256) void scan_final_kernel(int* __restrict__ cnt, int M,
                                                         const int* __restrict__ bscan,
                                                         int* __restrict__ offsets) {
    __shared__ int s[256];
    const int t = threadIdx.x;
    const int base = blockIdx.x * SB + t * 2;
    int a = (base < M) ? cnt[base] : 0;
    int b = (base + 1 < M) ? cnt[base + 1] : 0;
    const int tsum = a + b;
    s[t] = tsum;
    __syncthreads();
    #pragma unroll
    for (int o = 1; o < 256; o <<= 1) {
        int u = (t >= o) ? s[t - o] : 0;
        __syncthreads();
        s[t] += u;
        __syncthreads();
    }
    const int excl = s[t] - tsum + bscan[blockIdx.x];
    if (base < M)     { offsets[base] = excl;         cnt[base] = excl; }
    if (base + 1 < M) { offsets[base + 1] = excl + a; cnt[base + 1] = excl + a; }
}

__global__ __launch_bounds__(256) void sort_kernel(const int* __restrict__ src,
                                                   const int* __restrict__ dst, int E,
                                                   int* __restrict__ cursor,
                                                   int* __restrict__ sorted_src) {
    int e = blockIdx.x * 256 + threadIdx.x;
    if (e < E) {
        int pos = atomicAdd(&cursor[dst[e]], 1);
        sorted_src[pos] = src[e];
    }
}

// ---------------- fused gather-aggregate + GEMM ----------------
// One block = 64 output rows x all 512 cols, 512 threads (8 waves, 64x64/wave).
// Phase 1: wave w gather-aggregates rows w*8..w*8+7 in fp32, converts to bf16,
//   ds_write_b128 into a XOR-swizzled LDS A-tile. Lane owns cols lane*8..+7,
//   so its 8 floats form one 16B slot; stored slot = lane ^ (row&7) -> both
//   write and later fragment reads are 2-way bank aliasing (free).
// Phase 2 (after ONE barrier): barrier-free k-loop. A-fragments from LDS,
//   B-fragments straight from global wb (512KB, L2-resident & shared by all
//   blocks; each 16-lane fragment read covers full 64B lines). acc in f32.
// Eliminates: aggb HBM round-trip, per-k-step barriers/vmcnt drains, 4x
// A-tile re-reads of the old BN=128 grid, one launch.
__global__ __launch_bounds__(512, 2) void fused_kernel(const float* __restrict__ src_h,
                                                       const int* __restrict__ offsets,
                                                       const int* __restrict__ sorted_src,
                                                       const unsigned short* __restrict__ wb,
                                                       const float* __restrict__ bias,
                                                       float* __restrict__ out, int M) {
    __shared__ __align__(16) unsigned short As[FBM * D];   // 64 KB

    const int t = threadIdx.x;
    const int w = t >> 6;          // wave 0..7
    const int lane = t & 63;
    const int m0 = blockIdx.x * FBM;
    const float4* rb = (const float4*)src_h;   // row s = rb + s*128

    // ---- phase 1: gather-aggregate 8 rows per wave ----
    for (int rr = 0; rr < 8; ++rr) {
        const int r = w * 8 + rr;          // local row 0..63
        const int rg = m0 + r;
        int beg = 0, end = 0;
        if (rg < M) { beg = offsets[rg]; end = offsets[rg + 1]; }
        float4 a0 = {0.f, 0.f, 0.f, 0.f};
        float4 a1 = {0.f, 0.f, 0.f, 0.f};
        int e = beg;
        for (; e + 4 <= end; e += 4) {
            const int s0 = sorted_src[e];
            const int s1 = sorted_src[e + 1];
            const int s2 = sorted_src[e + 2];
            const int s3 = sorted_src[e + 3];
            float4 v00 = rb[(size_t)s0 * 128 + lane * 2];
            float4 v01 = rb[(size_t)s0 * 128 + lane * 2 + 1];
            float4 v10 = rb[(size_t)s1 * 128 + lane * 2];
            float4 v11 = rb[(size_t)s1 * 128 + lane * 2 + 1];
            float4 v20 = rb[(size_t)s2 * 128 + lane * 2];
            float4 v21 = rb[(size_t)s2 * 128 + lane * 2 + 1];
            float4 v30 = rb[(size_t)s3 * 128 + lane * 2];
            float4 v31 = rb[(size_t)s3 * 128 + lane * 2 + 1];
            facc(a0, v00); facc(a1, v01);
            facc(a0, v10); facc(a1, v11);
            facc(a0, v20); facc(a1, v21);
            facc(a0, v30); facc(a1, v31);
        }
        if (e + 2 <= end) {
            const int s0 = sorted_src[e];
            const int s1 = sorted_src[e + 1];
            float4 v00 = rb[(size_t)s0 * 128 + lane * 2];
            float4 v01 = rb[(size_t)s0 * 128 + lane * 2 + 1];
            float4 v10 = rb[(size_t)s1 * 128 + lane * 2];
            float4 v11 = rb[(size_t)s1 * 128 + lane * 2 + 1];
            facc(a0, v00); facc(a1, v01);
            facc(a0, v10); facc(a1, v11);
            e += 2;
        }
        if (e < end) {
            const int s0 = sorted_src[e];
            float4 v00 = rb[(size_t)s0 * 128 + lane * 2];
            float4 v01 = rb[(size_t)s0 * 128 + lane * 2 + 1];
            facc(a0, v00); facc(a1, v01);
        }
        union { bf16x8 v; unsigned short u[8]; } pk;
        pk.u[0] = bf16_rne(a0.x); pk.u[1] = bf16_rne(a0.y);
        pk.u[2] = bf16_rne(a0.z); pk.u[3] = bf16_rne(a0.w);
        pk.u[4] = bf16_rne(a1.x); pk.u[5] = bf16_rne(a1.y);
        pk.u[6] = bf16_rne(a1.z); pk.u[7] = bf16_rne(a1.w);
        const int slot = lane ^ rr;        // rr == (local row) & 7
        *(bf16x8*)&As[r * D + slot * 8] = pk.v;
    }
    __syncthreads();

    // ---- phase 2: barrier-free GEMM; wave w -> cols w*64..w*64+63 ----
    const int quad = lane >> 4;
    const int lr = lane & 15;
    f32x4 acc[4][4] = {};

    const unsigned short* wc0 = wb + (size_t)(w * 64 +  0 + lr) * D;
    const unsigned short* wc1 = wb + (size_t)(w * 64 + 16 + lr) * D;
    const unsigned short* wc2 = wb + (size_t)(w * 64 + 32 + lr) * D;
    const unsigned short* wc3 = wb + (size_t)(w * 64 + 48 + lr) * D;

    #pragma unroll 2
    for (int k0 = 0; k0 < D; k0 += 32) {
        bf16x8 af[4], bfr[4];
        const int ks = (k0 >> 3) + quad;
        #pragma unroll
        for (int i = 0; i < 4; ++i)
            af[i] = *(const bf16x8*)&As[(i * 16 + lr) * D + (ks ^ (lr & 7)) * 8];
        bfr[0] = *(const bf16x8*)(wc0 + k0 + quad * 8);
        bfr[1] = *(const bf16x8*)(wc1 + k0 + quad * 8);
        bfr[2] = *(const bf16x8*)(wc2 + k0 + quad * 8);
        bfr[3] = *(const bf16x8*)(wc3 + k0 + quad * 8);
        #pragma unroll
        for (int i = 0; i < 4; ++i)
            #pragma unroll
            for (int j = 0; j < 4; ++j)
                acc[i][j] = __builtin_amdgcn_mfma_f32_16x16x32_bf16(af[i], bfr[j], acc[i][j], 0, 0, 0);
    }

    // ---- epilogue ----
    #pragma unroll
    for (int j = 0; j < 4; ++j) {
        const int col = w * 64 + j * 16 + lr;
        const float bv = bias[col];
        #pragma unroll
        for (int i = 0; i < 4; ++i) {
            const int rbase = m0 + i * 16 + quad * 4;
            #pragma unroll
            for (int r = 0; r < 4; ++r) {
                const int row = rbase + r;
                if (row < M) out[(size_t)row * D + col] = acc[i][j][r] + bv;
            }
        }
    }
}

extern "C" void kernel_launch(void* const* d_in, const int* in_sizes, int n_in,
                              void* d_out, int out_size, void* d_ws, size_t ws_size,
                              hipStream_t stream) {
    const float* src_h = (const float*)d_in[0];
    const float* W     = (const float*)d_in[1];
    const float* b     = (const float*)d_in[2];
    const int*   si    = (const int*)d_in[3];
    const int*   di    = (const int*)d_in[4];
    const int M = in_sizes[0] / D;    // 50000
    const int E = in_sizes[3];        // 150000
    const int NB = (M + SB - 1) / SB; // scan blocks

    char* ws = (char*)d_ws;
    unsigned short* wb   = (unsigned short*)(ws + 51200000);       // D*D*2
    int* offsets         = (int*)(ws + 51724288);                  // (M+1)*4
    int* cnt             = (int*)(ws + 51924480);                  // M*4
    int* ssrc            = (int*)(ws + 52124480);                  // E*4
    int* bsum            = (int*)(ws + 52724480);                  // NB*4
    int* bscan           = (int*)(ws + 52726480);                  // NB*4

    hipMemsetAsync(cnt, 0, (size_t)M * sizeof(int), stream);
    const int HB = (E + 255) / 256;
    prep_kernel<<<dim3(512 + HB), 256, 0, stream>>>(W, wb, di, E, cnt);
    scan_reduce_kernel<<<dim3(NB), 256, 0, stream>>>(cnt, M, bsum);
    scan_bsum_kernel<<<1, 256, 0, stream>>>(bsum, NB, bscan, offsets, M);
    scan_final_kernel<<<dim3(NB), 256, 0, stream>>>(cnt, M, bscan, offsets);
    sort_kernel<<<dim3((E + 255) / 256), 256, 0, stream>>>(si, di, E, cnt, ssrc);

    const int FB = (M + FBM - 1) / FBM;                     // 782
    fused_kernel<<<dim3(FB), 512, 0, stream>>>(src_h, offsets, ssrc, wb, b,
                                               (float*)d_out, M);
}

// Round 3
// 313.518 us; speedup vs baseline: 1.0371x; 1.0371x over previous
//
#include <hip/hip_runtime.h>
#include <hip/hip_bf16.h>

#define D 512
#define BM 128
#define BN 128
#define BK 64
#define SB 512          // elements per scan block

typedef __attribute__((ext_vector_type(8))) short bf16x8;
typedef __attribute__((ext_vector_type(4))) float f32x4;

__device__ __forceinline__ unsigned short bf16_rne(float f) {
    union { float f; unsigned u; } v; v.f = f;
    return (unsigned short)((v.u + 0x7FFFu + ((v.u >> 16) & 1u)) >> 16);
}

__device__ __forceinline__ void gload16(const void* g, void* l) {
    __builtin_amdgcn_global_load_lds(
        (const __attribute__((address_space(1))) void*)g,
        (__attribute__((address_space(3))) void*)l,
        16, 0, 0);
}

__device__ __forceinline__ void facc(float4& a, const float4 v) {
    a.x += v.x; a.y += v.y; a.z += v.z; a.w += v.w;
}

// ---------------- W fp32->bf16 conversion fused with degree histogram ----------------
__global__ __launch_bounds__(256) void prep_kernel(const float* __restrict__ W,
                                                   unsigned short* __restrict__ wb,
                                                   const int* __restrict__ dst, int E,
                                                   int* __restrict__ cnt) {
    const int b = blockIdx.x;
    const int t = threadIdx.x;
    if (b < 512) {
        const int i = b * 256 + t;
        float2 v = ((const float2*)W)[i];
        unsigned r = ((unsigned)bf16_rne(v.x)) | (((unsigned)bf16_rne(v.y)) << 16);
        ((unsigned*)wb)[i] = r;
    } else {
        const int e = (b - 512) * 256 + t;
        if (e < E) atomicAdd(&cnt[dst[e]], 1);
    }
}

// ---------------- CSR build: 2-kernel scan + sort ----------------

__global__ __launch_bounds__(256) void scan_reduce_kernel(const int* __restrict__ cnt, int M,
                                                          int* __restrict__ bsum) {
    const int t = threadIdx.x;
    const int i0 = blockIdx.x * SB + t * 2;
    int v = 0;
    if (i0 < M)     v += cnt[i0];
    if (i0 + 1 < M) v += cnt[i0 + 1];
    #pragma unroll
    for (int o = 32; o > 0; o >>= 1) v += __shfl_down(v, o, 64);
    __shared__ int ws_[4];
    if ((t & 63) == 0) ws_[t >> 6] = v;
    __syncthreads();
    if (t == 0) bsum[blockIdx.x] = ws_[0] + ws_[1] + ws_[2] + ws_[3];
}

// Each block redundantly scans the (<=256) block sums in LDS, then applies its
// local 512-element scan. Replaces the serial single-block scan_bsum dispatch
// plus scan_final with ONE kernel (saves a boundary; no cross-block dependency
// beyond scan_reduce's completion).
__global__ __launch_bounds__(256) void scan_final_kernel(int* __restrict__ cnt, int M,
                                                         const int* __restrict__ bsum, int NB,
                                                         int* __restrict__ offsets) {
    __shared__ int sb[256];
    __shared__ int s[256];
    const int t = threadIdx.x;

    int bv = (t < NB) ? bsum[t] : 0;
    sb[t] = bv;
    __syncthreads();
    #pragma unroll
    for (int o = 1; o < 256; o <<= 1) {
        int u = (t >= o) ? sb[t - o] : 0;
        __syncthreads();
        sb[t] += u;
        __syncthreads();
    }
    if (blockIdx.x == 0 && t == 255) offsets[M] = sb[255];
    const int bexcl = (blockIdx.x > 0) ? sb[blockIdx.x - 1] : 0;

    const int base = blockIdx.x * SB + t * 2;
    int a = (base < M) ? cnt[base] : 0;
    int b = (base + 1 < M) ? cnt[base + 1] : 0;
    const int tsum = a + b;
    s[t] = tsum;
    __syncthreads();
    #pragma unroll
    for (int o = 1; o < 256; o <<= 1) {
        int u = (t >= o) ? s[t - o] : 0;
        __syncthreads();
        s[t] += u;
        __syncthreads();
    }
    const int excl = s[t] - tsum + bexcl;
    if (base < M)     { offsets[base] = excl;         cnt[base] = excl; }
    if (base + 1 < M) { offsets[base + 1] = excl + a; cnt[base + 1] = excl + a; }
}

__global__ __launch_bounds__(256) void sort_kernel(const int* __restrict__ src,
                                                   const int* __restrict__ dst, int E,
                                                   int* __restrict__ cursor,
                                                   int* __restrict__ sorted_src) {
    int e = blockIdx.x * 256 + threadIdx.x;
    if (e < E) {
        int pos = atomicAdd(&cursor[dst[e]], 1);
        sorted_src[pos] = src[e];
    }
}

// ---------------- gather-aggregate (no atomics), fp32 acc -> bf16 write ----------------
// wave-per-node, 4 nodes / 256-thread block, edge-batched 4/2/1 for MLP.
// High-TLP structure (12.5K blocks) -- R2 proved fusing this into the GEMM
// block kills the latency hiding; keep it split.
__global__ __launch_bounds__(256) void agg_kernel(const float* __restrict__ src_h,
                                                  const int* __restrict__ offsets,
                                                  const int* __restrict__ sorted_src,
                                                  unsigned short* __restrict__ aggb,
                                                  int M) {
    const int wv = threadIdx.x >> 6;
    const int lane = threadIdx.x & 63;
    const int d = blockIdx.x * 4 + wv;
    if (d >= M) return;
    const int beg = offsets[d];
    const int end = offsets[d + 1];
    const float4* rb = (const float4*)src_h;    // row s = rb + s*128

    float4 a0 = {0.f, 0.f, 0.f, 0.f};
    float4 a1 = {0.f, 0.f, 0.f, 0.f};
    int e = beg;

    for (; e + 4 <= end; e += 4) {
        const int s0 = sorted_src[e];
        const int s1 = sorted_src[e + 1];
        const int s2 = sorted_src[e + 2];
        const int s3 = sorted_src[e + 3];
        float4 v00 = rb[(size_t)s0 * 128 + lane];
        float4 v01 = rb[(size_t)s0 * 128 + 64 + lane];
        float4 v10 = rb[(size_t)s1 * 128 + lane];
        float4 v11 = rb[(size_t)s1 * 128 + 64 + lane];
        float4 v20 = rb[(size_t)s2 * 128 + lane];
        float4 v21 = rb[(size_t)s2 * 128 + 64 + lane];
        float4 v30 = rb[(size_t)s3 * 128 + lane];
        float4 v31 = rb[(size_t)s3 * 128 + 64 + lane];
        facc(a0, v00); facc(a1, v01);
        facc(a0, v10); facc(a1, v11);
        facc(a0, v20); facc(a1, v21);
        facc(a0, v30); facc(a1, v31);
    }
    if (e + 2 <= end) {
        const int s0 = sorted_src[e];
        const int s1 = sorted_src[e + 1];
        float4 v00 = rb[(size_t)s0 * 128 + lane];
        float4 v01 = rb[(size_t)s0 * 128 + 64 + lane];
        float4 v10 = rb[(size_t)s1 * 128 + lane];
        float4 v11 = rb[(size_t)s1 * 128 + 64 + lane];
        facc(a0, v00); facc(a1, v01);
        facc(a0, v10); facc(a1, v11);
        e += 2;
    }
    if (e < end) {
        const int s0 = sorted_src[e];
        float4 v00 = rb[(size_t)s0 * 128 + lane];
        float4 v01 = rb[(size_t)s0 * 128 + 64 + lane];
        facc(a0, v00); facc(a1, v01);
    }

    ushort4 o0, o1;
    o0.x = bf16_rne(a0.x); o0.y = bf16_rne(a0.y);
    o0.z = bf16_rne(a0.z); o0.w = bf16_rne(a0.w);
    o1.x = bf16_rne(a1.x); o1.y = bf16_rne(a1.y);
    o1.z = bf16_rne(a1.z); o1.w = bf16_rne(a1.w);
    *(ushort4*)(aggb + (size_t)d * D + lane * 4) = o0;
    *(ushort4*)(aggb + (size_t)d * D + 256 + lane * 4) = o1;
}

// ---------------- GEMM: out = aggb @ wb^T + bias ----------------
// BK=64: row stride in LDS = 128 B (full bank period), 8x 16B slots per row.
// Swizzle: element chunk kc of row r stored at slot kc ^ (r&7). Staging DMA is
// lane-linear in LDS (global_load_lds requirement); the swizzle is applied on
// the GLOBAL source column instead (q-independent since 32 | 8). Fragment
// reads: 16 lanes x distinct (row&7) -> all 8 slots x 4 banks = 32 banks
// covered twice -> 2-way aliasing, free. 8 k-steps instead of 16 halves the
// barrier/vmcnt-drain count; 32 MFMA per phase.
__global__ __launch_bounds__(256) void gemm_kernel(const unsigned short* __restrict__ A,
                                                   const unsigned short* __restrict__ B,
                                                   const float* __restrict__ bias,
                                                   float* __restrict__ out,
                                                   int M, int MB_tiles) {
    __shared__ __align__(16) unsigned short As[BM * BK];   // 16 KB
    __shared__ __align__(16) unsigned short Bs[BN * BK];   // 16 KB

    const int L = blockIdx.x;
    const int mb = (L >> 5) * 8 + (L & 7);   // blocks differing in nb differ by 8 -> same XCD
    const int nb = (L >> 3) & 3;
    if (mb >= MB_tiles) return;
    const int m0 = mb * BM;
    const int n0 = nb * BN;

    const int t = threadIdx.x;
    const int lane = t & 63;
    const int wave = t >> 6;
    const int wm = wave >> 1;
    const int wn = wave & 1;
    const int quad = lane >> 4;
    const int lr = lane & 15;

    // staging: issue q covers rows q*32 + (t>>3); global col chunk is the
    // inverse swizzle of the linear LDS slot (t&7): kc = (t&7) ^ ((t>>3)&7)
    const int srow = t >> 3;                               // 0..31
    const int scol = ((t & 7) ^ (srow & 7)) * 8;           // element offset in [0,64)
    int arow[4], brow[4];
    #pragma unroll
    for (int q = 0; q < 4; ++q) {
        arow[q] = min(m0 + q * 32 + srow, M - 1);
        brow[q] = n0 + q * 32 + srow;
    }

    // fragment read swizzle: kk half toggles slot bit2 -> +-32 elements
    const int fs0 = (quad ^ (lr & 7)) * 8;

    f32x4 acc[4][4] = {};

    for (int k0 = 0; k0 < D; k0 += BK) {
        #pragma unroll
        for (int q = 0; q < 4; ++q) {
            gload16(A + (size_t)arow[q] * D + k0 + scol, As + q * 2048 + t * 8);
            gload16(B + (size_t)brow[q] * D + k0 + scol, Bs + q * 2048 + t * 8);
        }
        __syncthreads();

        #pragma unroll
        for (int kk = 0; kk < 2; ++kk) {
            const int fs = fs0 ^ (kk << 5);
            bf16x8 af[4], bfr[4];
            #pragma unroll
            for (int i = 0; i < 4; ++i) {
                af[i]  = *(const bf16x8*)&As[(wm * 64 + i * 16 + lr) * BK + fs];
                bfr[i] = *(const bf16x8*)&Bs[(wn * 64 + i * 16 + lr) * BK + fs];
            }
            #pragma unroll
            for (int i = 0; i < 4; ++i)
                #pragma unroll
                for (int j = 0; j < 4; ++j)
                    acc[i][j] = __builtin_amdgcn_mfma_f32_16x16x32_bf16(af[i], bfr[j], acc[i][j], 0, 0, 0);
        }
        __syncthreads();
    }

    #pragma unroll
    for (int j = 0; j < 4; ++j) {
        const int col = n0 + wn * 64 + j * 16 + lr;
        const float bv = bias[col];
        #pragma unroll
        for (int i = 0; i < 4; ++i) {
            const int rbase = m0 + wm * 64 + i * 16 + quad * 4;
            #pragma unroll
            for (int r = 0; r < 4; ++r) {
                const int row = rbase + r;
                if (row < M) out[(size_t)row * D + col] = acc[i][j][r] + bv;
            }
        }
    }
}

extern "C" void kernel_launch(void* const* d_in, const int* in_sizes, int n_in,
                              void* d_out, int out_size, void* d_ws, size_t ws_size,
                              hipStream_t stream) {
    const float* src_h = (const float*)d_in[0];
    const float* W     = (const float*)d_in[1];
    const float* b     = (const float*)d_in[2];
    const int*   si    = (const int*)d_in[3];
    const int*   di    = (const int*)d_in[4];
    const int M = in_sizes[0] / D;    // 50000
    const int E = in_sizes[3];        // 150000
    const int NB = (M + SB - 1) / SB; // scan blocks (98)

    char* ws = (char*)d_ws;
    unsigned short* aggb = (unsigned short*)ws;                    // M*D*2
    unsigned short* wb   = (unsigned short*)(ws + 51200000);       // D*D*2
    int* offsets         = (int*)(ws + 51724288);                  // (M+1)*4
    int* cnt             = (int*)(ws + 51924480);                  // M*4
    int* ssrc            = (int*)(ws + 52124480);                  // E*4
    int* bsum            = (int*)(ws + 52724480);                  // NB*4

    hipMemsetAsync(cnt, 0, (size_t)M * sizeof(int), stream);
    const int HB = (E + 255) / 256;
    prep_kernel<<<dim3(512 + HB), 256, 0, stream>>>(W, wb, di, E, cnt);
    scan_reduce_kernel<<<dim3(NB), 256, 0, stream>>>(cnt, M, bsum);
    scan_final_kernel<<<dim3(NB), 256, 0, stream>>>(cnt, M, bsum, NB, offsets);
    sort_kernel<<<dim3((E + 255) / 256), 256, 0, stream>>>(si, di, E, cnt, ssrc);
    agg_kernel<<<dim3((M + 3) / 4), 256, 0, stream>>>(src_h, offsets, ssrc, aggb, M);

    const int MB_tiles = (M + BM - 1) / BM;                 // 391
    const int ngrid = ((MB_tiles + 7) / 8) * 32;            // 8 m-tiles x 4 n-tiles per group
    gemm_kernel<<<dim3(ngrid), 256, 0, stream>>>(aggb, wb, b, (float*)d_out, M, MB_tiles);
}

// Round 4
// 274.617 us; speedup vs baseline: 1.1840x; 1.1417x over previous
//
#include <hip/hip_runtime.h>
#include <hip/hip_bf16.h>

#define D 512
#define BM 128
#define BN 128
#define BK 32
#define SB 512          // elements per scan block

typedef __attribute__((ext_vector_type(8))) short bf16x8;
typedef __attribute__((ext_vector_type(4))) float f32x4;

__device__ __forceinline__ unsigned short bf16_rne(float f) {
    union { float f; unsigned u; } v; v.f = f;
    return (unsigned short)((v.u + 0x7FFFu + ((v.u >> 16) & 1u)) >> 16);
}

__device__ __forceinline__ void gload16(const void* g, void* l) {
    __builtin_amdgcn_global_load_lds(
        (const __attribute__((address_space(1))) void*)g,
        (__attribute__((address_space(3))) void*)l,
        16, 0, 0);
}

__device__ __forceinline__ void facc(float4& a, const float4 v) {
    a.x += v.x; a.y += v.y; a.z += v.z; a.w += v.w;
}

// ---------------- W fp32->bf16 conversion fused with degree histogram ----------------
__global__ __launch_bounds__(256) void prep_kernel(const float* __restrict__ W,
                                                   unsigned short* __restrict__ wb,
                                                   const int* __restrict__ dst, int E,
                                                   int* __restrict__ cnt) {
    const int b = blockIdx.x;
    const int t = threadIdx.x;
    if (b < 512) {
        const int i = b * 256 + t;
        float2 v = ((const float2*)W)[i];
        unsigned r = ((unsigned)bf16_rne(v.x)) | (((unsigned)bf16_rne(v.y)) << 16);
        ((unsigned*)wb)[i] = r;
    } else {
        const int e = (b - 512) * 256 + t;
        if (e < E) atomicAdd(&cnt[dst[e]], 1);
    }
}

// ---------------- CSR build: 2-kernel scan + sort ----------------

__global__ __launch_bounds__(256) void scan_reduce_kernel(const int* __restrict__ cnt, int M,
                                                          int* __restrict__ bsum) {
    const int t = threadIdx.x;
    const int i0 = blockIdx.x * SB + t * 2;
    int v = 0;
    if (i0 < M)     v += cnt[i0];
    if (i0 + 1 < M) v += cnt[i0 + 1];
    #pragma unroll
    for (int o = 32; o > 0; o >>= 1) v += __shfl_down(v, o, 64);
    __shared__ int ws_[4];
    if ((t & 63) == 0) ws_[t >> 6] = v;
    __syncthreads();
    if (t == 0) bsum[blockIdx.x] = ws_[0] + ws_[1] + ws_[2] + ws_[3];
}

__global__ __launch_bounds__(256) void scan_final_kernel(int* __restrict__ cnt, int M,
                                                         const int* __restrict__ bsum, int NB,
                                                         int* __restrict__ offsets) {
    __shared__ int sb[256];
    __shared__ int s[256];
    const int t = threadIdx.x;

    int bv = (t < NB) ? bsum[t] : 0;
    sb[t] = bv;
    __syncthreads();
    #pragma unroll
    for (int o = 1; o < 256; o <<= 1) {
        int u = (t >= o) ? sb[t - o] : 0;
        __syncthreads();
        sb[t] += u;
        __syncthreads();
    }
    if (blockIdx.x == 0 && t == 255) offsets[M] = sb[255];
    const int bexcl = (blockIdx.x > 0) ? sb[blockIdx.x - 1] : 0;

    const int base = blockIdx.x * SB + t * 2;
    int a = (base < M) ? cnt[base] : 0;
    int b = (base + 1 < M) ? cnt[base + 1] : 0;
    const int tsum = a + b;
    s[t] = tsum;
    __syncthreads();
    #pragma unroll
    for (int o = 1; o < 256; o <<= 1) {
        int u = (t >= o) ? s[t - o] : 0;
        __syncthreads();
        s[t] += u;
        __syncthreads();
    }
    const int excl = s[t] - tsum + bexcl;
    if (base < M)     { offsets[base] = excl;         cnt[base] = excl; }
    if (base + 1 < M) { offsets[base + 1] = excl + a; cnt[base + 1] = excl + a; }
}

__global__ __launch_bounds__(256) void sort_kernel(const int* __restrict__ src,
                                                   const int* __restrict__ dst, int E,
                                                   int* __restrict__ cursor,
                                                   int* __restrict__ sorted_src) {
    int e = blockIdx.x * 256 + threadIdx.x;
    if (e < E) {
        int pos = atomicAdd(&cursor[dst[e]], 1);
        sorted_src[pos] = src[e];
    }
}

// ---------------- gather-aggregate (no atomics), fp32 acc -> bf16 write ----------------
__global__ __launch_bounds__(256) void agg_kernel(const float* __restrict__ src_h,
                                                  const int* __restrict__ offsets,
                                                  const int* __restrict__ sorted_src,
                                                  unsigned short* __restrict__ aggb,
                                                  int M) {
    const int wv = threadIdx.x >> 6;
    const int lane = threadIdx.x & 63;
    const int d = blockIdx.x * 4 + wv;
    if (d >= M) return;
    const int beg = offsets[d];
    const int end = offsets[d + 1];
    const float4* rb = (const float4*)src_h;    // row s = rb + s*128

    float4 a0 = {0.f, 0.f, 0.f, 0.f};
    float4 a1 = {0.f, 0.f, 0.f, 0.f};
    int e = beg;

    for (; e + 4 <= end; e += 4) {
        const int s0 = sorted_src[e];
        const int s1 = sorted_src[e + 1];
        const int s2 = sorted_src[e + 2];
        const int s3 = sorted_src[e + 3];
        float4 v00 = rb[(size_t)s0 * 128 + lane];
        float4 v01 = rb[(size_t)s0 * 128 + 64 + lane];
        float4 v10 = rb[(size_t)s1 * 128 + lane];
        float4 v11 = rb[(size_t)s1 * 128 + 64 + lane];
        float4 v20 = rb[(size_t)s2 * 128 + lane];
        float4 v21 = rb[(size_t)s2 * 128 + 64 + lane];
        float4 v30 = rb[(size_t)s3 * 128 + lane];
        float4 v31 = rb[(size_t)s3 * 128 + 64 + lane];
        facc(a0, v00); facc(a1, v01);
        facc(a0, v10); facc(a1, v11);
        facc(a0, v20); facc(a1, v21);
        facc(a0, v30); facc(a1, v31);
    }
    if (e + 2 <= end) {
        const int s0 = sorted_src[e];
        const int s1 = sorted_src[e + 1];
        float4 v00 = rb[(size_t)s0 * 128 + lane];
        float4 v01 = rb[(size_t)s0 * 128 + 64 + lane];
        float4 v10 = rb[(size_t)s1 * 128 + lane];
        float4 v11 = rb[(size_t)s1 * 128 + 64 + lane];
        facc(a0, v00); facc(a1, v01);
        facc(a0, v10); facc(a1, v11);
        e += 2;
    }
    if (e < end) {
        const int s0 = sorted_src[e];
        float4 v00 = rb[(size_t)s0 * 128 + lane];
        float4 v01 = rb[(size_t)s0 * 128 + 64 + lane];
        facc(a0, v00); facc(a1, v01);
    }

    ushort4 o0, o1;
    o0.x = bf16_rne(a0.x); o0.y = bf16_rne(a0.y);
    o0.z = bf16_rne(a0.z); o0.w = bf16_rne(a0.w);
    o1.x = bf16_rne(a1.x); o1.y = bf16_rne(a1.y);
    o1.z = bf16_rne(a1.z); o1.w = bf16_rne(a1.w);
    *(ushort4*)(aggb + (size_t)d * D + lane * 4) = o0;
    *(ushort4*)(aggb + (size_t)d * D + 256 + lane * 4) = o1;
}

// ---------------- GEMM: out = aggb @ wb^T + bias ----------------
// T3-minimum pipeline: double-buffered LDS (2x16KB), stage(next) issued
// BEFORE computing cur, then ONE raw s_barrier per k-step preceded by an
// explicit vmcnt(0) -- the next-tile loads fly during the entire
// ds_read+MFMA phase instead of being drained cold by __syncthreads()'s
// implicit vmcnt(0) (the m97-ceiling mechanism). Safety: ds_reads of
// buf[cur] complete before the MFMAs that consume them (compiler lgkmcnt),
// which precede the barrier; stage into buf[cur] happens only after the
// NEXT barrier. XOR-swizzle identical to the verified R0/R1 scheme.
// Epilogue transposed: acc = mfma(bfr, af) puts 4 consecutive COLUMNS in
// each lane's regs -> float4 stores + float4 bias.
__global__ __launch_bounds__(256) void gemm_kernel(const unsigned short* __restrict__ A,
                                                   const unsigned short* __restrict__ B,
                                                   const float* __restrict__ bias,
                                                   float* __restrict__ out,
                                                   int M, int MB_tiles) {
    __shared__ __align__(16) unsigned short As[2 * BM * BK];   // 16 KB
    __shared__ __align__(16) unsigned short Bs[2 * BN * BK];   // 16 KB

    const int L = blockIdx.x;
    const int mb = (L >> 5) * 8 + (L & 7);   // blocks differing in nb differ by 8 -> same XCD
    const int nb = (L >> 3) & 3;
    if (mb >= MB_tiles) return;
    const int m0 = mb * BM;
    const int n0 = nb * BN;

    const int t = threadIdx.x;
    const int lane = t & 63;
    const int wave = t >> 6;
    const int wm = wave >> 1;
    const int wn = wave & 1;
    const int quad = lane >> 4;
    const int lr = lane & 15;

    // staging: thread t fills LDS offset t*16B = (row = t>>2, slot = t&3);
    // the k-chunk in that slot is kc = slot ^ ((row>>1)&3)
    const int srow = t >> 2;
    const int scol = ((t & 3) ^ ((t >> 3) & 3)) * 8;
    const int arow0 = min(m0 + srow, M - 1);
    const int arow1 = min(m0 + 64 + srow, M - 1);
    const int brow0 = n0 + srow;
    const int brow1 = n0 + 64 + srow;
    const unsigned short* ag0 = A + (size_t)arow0 * D + scol;
    const unsigned short* ag1 = A + (size_t)arow1 * D + scol;
    const unsigned short* bg0 = B + (size_t)brow0 * D + scol;
    const unsigned short* bg1 = B + (size_t)brow1 * D + scol;

    // fragment read swizzle: slot = quad ^ ((r>>1)&3); r%16 == lr -> lane-only
    const int fsw = (quad ^ ((lr >> 1) & 3)) * 8;

    f32x4 acc[4][4] = {};

    // prologue: stage tile 0 into buffer 0
    gload16(ag0, As + t * 8);
    gload16(ag1, As + 2048 + t * 8);
    gload16(bg0, Bs + t * 8);
    gload16(bg1, Bs + 2048 + t * 8);
    asm volatile("s_waitcnt vmcnt(0)" ::: "memory");
    __builtin_amdgcn_s_barrier();

    for (int kt = 0; kt < 16; ++kt) {
        const int cur = (kt & 1) * 4096;
        const int nxt = 4096 - cur;
        if (kt + 1 < 16) {
            const int k0n = (kt + 1) * BK;
            gload16(ag0 + k0n, As + nxt + t * 8);
            gload16(ag1 + k0n, As + nxt + 2048 + t * 8);
            gload16(bg0 + k0n, Bs + nxt + t * 8);
            gload16(bg1 + k0n, Bs + nxt + 2048 + t * 8);
        }

        bf16x8 af[4], bfr[4];
        #pragma unroll
        for (int i = 0; i < 4; ++i) {
            af[i]  = *(const bf16x8*)&As[cur + (wm * 64 + i * 16 + lr) * BK + fsw];
            bfr[i] = *(const bf16x8*)&Bs[cur + (wn * 64 + i * 16 + lr) * BK + fsw];
        }
        #pragma unroll
        for (int i = 0; i < 4; ++i)
            #pragma unroll
            for (int j = 0; j < 4; ++j)
                acc[i][j] = __builtin_amdgcn_mfma_f32_16x16x32_bf16(bfr[j], af[i], acc[i][j], 0, 0, 0);

        if (kt + 1 < 16) {
            asm volatile("s_waitcnt vmcnt(0)" ::: "memory");
            __builtin_amdgcn_s_barrier();
        }
    }

    // transposed epilogue: lane holds out[m][nbase..nbase+3] per (i,j)
    #pragma unroll
    for (int i = 0; i < 4; ++i) {
        const int row = m0 + wm * 64 + i * 16 + lr;
        if (row >= M) continue;
        #pragma unroll
        for (int j = 0; j < 4; ++j) {
            const int colb = n0 + wn * 64 + j * 16 + quad * 4;
            const float4 bv = *(const float4*)(bias + colb);
            float4 o;
            o.x = acc[i][j][0] + bv.x;
            o.y = acc[i][j][1] + bv.y;
            o.z = acc[i][j][2] + bv.z;
            o.w = acc[i][j][3] + bv.w;
            *(float4*)(out + (size_t)row * D + colb) = o;
        }
    }
}

extern "C" void kernel_launch(void* const* d_in, const int* in_sizes, int n_in,
                              void* d_out, int out_size, void* d_ws, size_t ws_size,
                              hipStream_t stream) {
    const float* src_h = (const float*)d_in[0];
    const float* W     = (const float*)d_in[1];
    const float* b     = (const float*)d_in[2];
    const int*   si    = (const int*)d_in[3];
    const int*   di    = (const int*)d_in[4];
    const int M = in_sizes[0] / D;    // 50000
    const int E = in_sizes[3];        // 150000
    const int NB = (M + SB - 1) / SB; // scan blocks (98)

    char* ws = (char*)d_ws;
    unsigned short* aggb = (unsigned short*)ws;                    // M*D*2
    unsigned short* wb   = (unsigned short*)(ws + 51200000);       // D*D*2
    int* offsets         = (int*)(ws + 51724288);                  // (M+1)*4
    int* cnt             = (int*)(ws + 51924480);                  // M*4
    int* ssrc            = (int*)(ws + 52124480);                  // E*4
    int* bsum            = (int*)(ws + 52724480);                  // NB*4

    hipMemsetAsync(cnt, 0, (size_t)M * sizeof(int), stream);
    const int HB = (E + 255) / 256;
    prep_kernel<<<dim3(512 + HB), 256, 0, stream>>>(W, wb, di, E, cnt);
    scan_reduce_kernel<<<dim3(NB), 256, 0, stream>>>(cnt, M, bsum);
    scan_final_kernel<<<dim3(NB), 256, 0, stream>>>(cnt, M, bsum, NB, offsets);
    sort_kernel<<<dim3((E + 255) / 256), 256, 0, stream>>>(si, di, E, cnt, ssrc);
    agg_kernel<<<dim3((M + 3) / 4), 256, 0, stream>>>(src_h, offsets, ssrc, aggb, M);

    const int MB_tiles = (M + BM - 1) / BM;                 // 391
    const int ngrid = ((MB_tiles + 7) / 8) * 32;            // 8 m-tiles x 4 n-tiles per group
    gemm_kernel<<<dim3(ngrid), 256, 0, stream>>>(aggb, wb, b, (float*)d_out, M, MB_tiles);
}